// Round 1
// baseline (4139.445 us; speedup 1.0000x reference)
//
#include <hip/hip_runtime.h>

// LightGCN propagation: 3 sparse layers over a fixed bipartite graph.
// Strategy: build CSR per call (counting sort), then atomic-free gather
// layers with one wave per row (lane = embedding dim, EMB=64 = wave size).

#define EMB 64

__global__ void init_kernel(const float4* __restrict__ ue, const float4* __restrict__ ie,
                            float4* __restrict__ emb0, float4* __restrict__ acc,
                            int nu4, int tot4) {
    int i = blockIdx.x * blockDim.x + threadIdx.x;
    if (i >= tot4) return;
    float4 v = (i < nu4) ? ue[i] : ie[i - nu4];
    emb0[i] = v;
    acc[i]  = v;
}

__global__ void hist_kernel(const int* __restrict__ rows, int* __restrict__ cnt, int nnz) {
    int i = blockIdx.x * blockDim.x + threadIdx.x;
    if (i < nnz) atomicAdd(&cnt[rows[i]], 1);
}

// ---- 3-kernel exclusive scan over M=N+1 counts (2048 elems / block) ----
__global__ void scan1(const int* __restrict__ cnt, int* __restrict__ bsum, int M) {
    __shared__ int s[256];
    int tid  = threadIdx.x;
    int base = blockIdx.x * 2048 + tid * 8;
    int t = 0;
#pragma unroll
    for (int j = 0; j < 8; ++j) { int i = base + j; if (i < M) t += cnt[i]; }
    s[tid] = t; __syncthreads();
    for (int off = 128; off > 0; off >>= 1) {
        if (tid < off) s[tid] += s[tid + off];
        __syncthreads();
    }
    if (tid == 0) bsum[blockIdx.x] = s[0];
}

// single block; requires nb <= 256 (here nb = ceil(300001/2048) = 147)
__global__ void scan2(int* bsum, int nb) {
    __shared__ int s[256];
    int tid = threadIdx.x;
    int x = (tid < nb) ? bsum[tid] : 0;
    int orig = x;
    s[tid] = x; __syncthreads();
    for (int off = 1; off < 256; off <<= 1) {
        int y = (tid >= off) ? s[tid - off] : 0;
        __syncthreads();
        x += y; s[tid] = x; __syncthreads();
    }
    if (tid < nb) bsum[tid] = x - orig;   // exclusive
}

__global__ void scan3(const int* __restrict__ cnt, const int* __restrict__ bsum,
                      int* __restrict__ row_ptr, int* __restrict__ cursor, int M) {
    __shared__ int s[256];
    int tid  = threadIdx.x;
    int base = blockIdx.x * 2048 + tid * 8;
    int v[8]; int t = 0;
#pragma unroll
    for (int j = 0; j < 8; ++j) { int i = base + j; v[j] = (i < M) ? cnt[i] : 0; t += v[j]; }
    int x = t;
    s[tid] = x; __syncthreads();
    for (int off = 1; off < 256; off <<= 1) {
        int y = (tid >= off) ? s[tid - off] : 0;
        __syncthreads();
        x += y; s[tid] = x; __syncthreads();
    }
    int run = bsum[blockIdx.x] + (x - t);   // exclusive prefix for this thread
#pragma unroll
    for (int j = 0; j < 8; ++j) {
        int i = base + j;
        if (i < M) {
            row_ptr[i] = run;
            if (i < M - 1) cursor[i] = run;  // cursor has N entries
        }
        run += v[j];
    }
}

// counting-sort scatter: edge e -> slot in its row's CSR segment
__global__ void scatter_kernel(const int* __restrict__ rows, const int* __restrict__ cols,
                               const float* __restrict__ vals, int* __restrict__ cursor,
                               int2* __restrict__ edges, int nnz) {
    int i = blockIdx.x * blockDim.x + threadIdx.x;
    if (i >= nnz) return;
    int r = rows[i];
    int p = atomicAdd(&cursor[r], 1);
    edges[p] = make_int2(cols[i], __float_as_int(vals[i]));
}

// one wave per row; lane = dim. Edge data is a wave-broadcast 8B load,
// embedding gather is a fully coalesced 256B read across the wave.
__global__ void layer_kernel(const int* __restrict__ row_ptr, const int2* __restrict__ edges,
                             const float* __restrict__ embin, float* __restrict__ embout,
                             float* __restrict__ acc, int N) {
    int row  = (int)((blockIdx.x * blockDim.x + threadIdx.x) >> 6);
    int lane = threadIdx.x & 63;
    if (row >= N) return;
    int s = row_ptr[row], e = row_ptr[row + 1];
    float sum = 0.f;
    for (int i = s; i < e; ++i) {
        int2 cv = edges[i];
        sum = fmaf(__int_as_float(cv.y), embin[(size_t)cv.x * EMB + lane], sum);
    }
    size_t idx = (size_t)row * EMB + lane;
    embout[idx] = sum;
    acc[idx]   += sum;
}

__global__ void scale_kernel(float4* __restrict__ out, int tot4) {
    int i = blockIdx.x * blockDim.x + threadIdx.x;
    if (i >= tot4) return;
    float4 v = out[i];
    v.x *= 0.25f; v.y *= 0.25f; v.z *= 0.25f; v.w *= 0.25f;
    out[i] = v;
}

extern "C" void kernel_launch(void* const* d_in, const int* in_sizes, int n_in,
                              void* d_out, int out_size, void* d_ws, size_t ws_size,
                              hipStream_t stream) {
    const float* ue   = (const float*)d_in[0];
    const float* ie   = (const float*)d_in[1];
    const float* vals = (const float*)d_in[2];
    const int*   rows = (const int*)d_in[3];
    const int*   cols = (const int*)d_in[4];

    int nu  = in_sizes[0] / EMB;
    int ni  = in_sizes[1] / EMB;
    int N   = nu + ni;
    int nnz = in_sizes[2];
    int M   = N + 1;

    // workspace carve-out (256B aligned)
    char*  w   = (char*)d_ws;
    size_t off = 0;
    auto alloc = [&](size_t bytes) -> void* {
        void* p = w + off;
        off = (off + bytes + 255) & ~(size_t)255;
        return p;
    };
    float* emb0    = (float*)alloc((size_t)N * EMB * sizeof(float));
    float* emb1    = (float*)alloc((size_t)N * EMB * sizeof(float));
    int2*  edges   = (int2*) alloc((size_t)nnz * sizeof(int2));
    int*   cnt     = (int*)  alloc((size_t)M * sizeof(int));
    int*   row_ptr = (int*)  alloc((size_t)M * sizeof(int));
    int*   cursor  = (int*)  alloc((size_t)N * sizeof(int));
    int*   bsum    = (int*)  alloc(1024 * sizeof(int));
    float* acc     = (float*)d_out;   // accumulator lives in the output buffer

    hipMemsetAsync(cnt, 0, (size_t)M * sizeof(int), stream);

    int tot4 = N * EMB / 4, nu4 = nu * EMB / 4;
    init_kernel<<<(tot4 + 255) / 256, 256, 0, stream>>>(
        (const float4*)ue, (const float4*)ie, (float4*)emb0, (float4*)acc, nu4, tot4);

    hist_kernel<<<(nnz + 255) / 256, 256, 0, stream>>>(rows, cnt, nnz);

    int nb = (M + 2047) / 2048;
    scan1<<<nb, 256, 0, stream>>>(cnt, bsum, M);
    scan2<<<1,  256, 0, stream>>>(bsum, nb);
    scan3<<<nb, 256, 0, stream>>>(cnt, bsum, row_ptr, cursor, M);

    scatter_kernel<<<(nnz + 255) / 256, 256, 0, stream>>>(rows, cols, vals, cursor, edges, nnz);

    int lgrid = (N + 3) / 4;   // 4 waves (rows) per 256-thread block
    layer_kernel<<<lgrid, 256, 0, stream>>>(row_ptr, edges, emb0, emb1, acc, N);
    layer_kernel<<<lgrid, 256, 0, stream>>>(row_ptr, edges, emb1, emb0, acc, N);
    layer_kernel<<<lgrid, 256, 0, stream>>>(row_ptr, edges, emb0, emb1, acc, N);

    scale_kernel<<<(tot4 + 255) / 256, 256, 0, stream>>>((float4*)acc, tot4);
}

// Round 2
// 2170.429 us; speedup vs baseline: 1.9072x; 1.9072x over previous
//
#include <hip/hip_runtime.h>

// LightGCN propagation: 3 sparse layers over a fixed bipartite graph.
// R2: unroll gather x8 for memory-level parallelism (R1 was latency-bound,
// VGPR=8, 18% HBM); fuse init into layer0 and scale into layer2.

#define EMB 64

__global__ void hist_kernel(const int* __restrict__ rows, int* __restrict__ cnt, int nnz) {
    int i = blockIdx.x * blockDim.x + threadIdx.x;
    if (i < nnz) atomicAdd(&cnt[rows[i]], 1);
}

// ---- 3-kernel exclusive scan over M=N+1 counts (2048 elems / block) ----
__global__ void scan1(const int* __restrict__ cnt, int* __restrict__ bsum, int M) {
    __shared__ int s[256];
    int tid  = threadIdx.x;
    int base = blockIdx.x * 2048 + tid * 8;
    int t = 0;
#pragma unroll
    for (int j = 0; j < 8; ++j) { int i = base + j; if (i < M) t += cnt[i]; }
    s[tid] = t; __syncthreads();
    for (int off = 128; off > 0; off >>= 1) {
        if (tid < off) s[tid] += s[tid + off];
        __syncthreads();
    }
    if (tid == 0) bsum[blockIdx.x] = s[0];
}

// single block; requires nb <= 256 (here nb = ceil(300001/2048) = 147)
__global__ void scan2(int* bsum, int nb) {
    __shared__ int s[256];
    int tid = threadIdx.x;
    int x = (tid < nb) ? bsum[tid] : 0;
    int orig = x;
    s[tid] = x; __syncthreads();
    for (int off = 1; off < 256; off <<= 1) {
        int y = (tid >= off) ? s[tid - off] : 0;
        __syncthreads();
        x += y; s[tid] = x; __syncthreads();
    }
    if (tid < nb) bsum[tid] = x - orig;   // exclusive
}

__global__ void scan3(const int* __restrict__ cnt, const int* __restrict__ bsum,
                      int* __restrict__ row_ptr, int* __restrict__ cursor, int M) {
    __shared__ int s[256];
    int tid  = threadIdx.x;
    int base = blockIdx.x * 2048 + tid * 8;
    int v[8]; int t = 0;
#pragma unroll
    for (int j = 0; j < 8; ++j) { int i = base + j; v[j] = (i < M) ? cnt[i] : 0; t += v[j]; }
    int x = t;
    s[tid] = x; __syncthreads();
    for (int off = 1; off < 256; off <<= 1) {
        int y = (tid >= off) ? s[tid - off] : 0;
        __syncthreads();
        x += y; s[tid] = x; __syncthreads();
    }
    int run = bsum[blockIdx.x] + (x - t);   // exclusive prefix for this thread
#pragma unroll
    for (int j = 0; j < 8; ++j) {
        int i = base + j;
        if (i < M) {
            row_ptr[i] = run;
            if (i < M - 1) cursor[i] = run;  // cursor has N entries
        }
        run += v[j];
    }
}

// counting-sort scatter: edge e -> slot in its row's CSR segment
__global__ void scatter_kernel(const int* __restrict__ rows, const int* __restrict__ cols,
                               const float* __restrict__ vals, int* __restrict__ cursor,
                               int2* __restrict__ edges, int nnz) {
    int i = blockIdx.x * blockDim.x + threadIdx.x;
    if (i >= nnz) return;
    int r = rows[i];
    int p = atomicAdd(&cursor[r], 1);
    edges[p] = make_int2(cols[i], __float_as_int(vals[i]));
}

__device__ __forceinline__ const float* col_ptr(int c, const float* ue, const float* ie, int nu) {
    return (c < nu) ? (ue + (size_t)c * EMB) : (ie + ((size_t)c - nu) * EMB);
}

// One wave per row; lane = dim. Unrolled x8: 8 independent 256B gathers in
// flight per wave to cover HBM latency (R1 had ~1, was latency-bound).
// MODE 0: first layer (reads ue/ie directly, inits acc = e0 + sum)
// MODE 1: middle layer (acc += sum)
// MODE 2: last layer   (acc = (acc + sum) * 0.25, no embout write)
template<int MODE>
__global__ __launch_bounds__(256) void layer_kernel(
    const int* __restrict__ row_ptr, const int2* __restrict__ edges,
    const float* __restrict__ embin, const float* __restrict__ ue,
    const float* __restrict__ ie, float* __restrict__ embout,
    float* __restrict__ acc, int N, int nu)
{
    int row  = (int)((blockIdx.x * blockDim.x + threadIdx.x) >> 6);
    int lane = threadIdx.x & 63;
    if (row >= N) return;
    int s = row_ptr[row], e = row_ptr[row + 1];
    float sum0 = 0.f, sum1 = 0.f, sum2 = 0.f, sum3 = 0.f;
    int i = s;
    for (; i + 8 <= e; i += 8) {
        int2 c0 = edges[i+0], c1 = edges[i+1], c2 = edges[i+2], c3 = edges[i+3];
        int2 c4 = edges[i+4], c5 = edges[i+5], c6 = edges[i+6], c7 = edges[i+7];
        float g0, g1, g2, g3, g4, g5, g6, g7;
        if (MODE == 0) {
            g0 = col_ptr(c0.x, ue, ie, nu)[lane];
            g1 = col_ptr(c1.x, ue, ie, nu)[lane];
            g2 = col_ptr(c2.x, ue, ie, nu)[lane];
            g3 = col_ptr(c3.x, ue, ie, nu)[lane];
            g4 = col_ptr(c4.x, ue, ie, nu)[lane];
            g5 = col_ptr(c5.x, ue, ie, nu)[lane];
            g6 = col_ptr(c6.x, ue, ie, nu)[lane];
            g7 = col_ptr(c7.x, ue, ie, nu)[lane];
        } else {
            g0 = embin[(size_t)c0.x * EMB + lane];
            g1 = embin[(size_t)c1.x * EMB + lane];
            g2 = embin[(size_t)c2.x * EMB + lane];
            g3 = embin[(size_t)c3.x * EMB + lane];
            g4 = embin[(size_t)c4.x * EMB + lane];
            g5 = embin[(size_t)c5.x * EMB + lane];
            g6 = embin[(size_t)c6.x * EMB + lane];
            g7 = embin[(size_t)c7.x * EMB + lane];
        }
        sum0 = fmaf(__int_as_float(c0.y), g0, sum0);
        sum1 = fmaf(__int_as_float(c1.y), g1, sum1);
        sum2 = fmaf(__int_as_float(c2.y), g2, sum2);
        sum3 = fmaf(__int_as_float(c3.y), g3, sum3);
        sum0 = fmaf(__int_as_float(c4.y), g4, sum0);
        sum1 = fmaf(__int_as_float(c5.y), g5, sum1);
        sum2 = fmaf(__int_as_float(c6.y), g6, sum2);
        sum3 = fmaf(__int_as_float(c7.y), g7, sum3);
    }
    for (; i < e; ++i) {
        int2 cv = edges[i];
        float g = (MODE == 0) ? col_ptr(cv.x, ue, ie, nu)[lane]
                              : embin[(size_t)cv.x * EMB + lane];
        sum0 = fmaf(__int_as_float(cv.y), g, sum0);
    }
    float sum = (sum0 + sum1) + (sum2 + sum3);
    size_t idx = (size_t)row * EMB + lane;
    if (MODE != 2) embout[idx] = sum;
    if (MODE == 0) {
        float base = (row < nu) ? ue[idx] : ie[idx - (size_t)nu * EMB];
        acc[idx] = base + sum;
    } else if (MODE == 1) {
        acc[idx] += sum;
    } else {
        acc[idx] = (acc[idx] + sum) * 0.25f;
    }
}

extern "C" void kernel_launch(void* const* d_in, const int* in_sizes, int n_in,
                              void* d_out, int out_size, void* d_ws, size_t ws_size,
                              hipStream_t stream) {
    const float* ue   = (const float*)d_in[0];
    const float* ie   = (const float*)d_in[1];
    const float* vals = (const float*)d_in[2];
    const int*   rows = (const int*)d_in[3];
    const int*   cols = (const int*)d_in[4];

    int nu  = in_sizes[0] / EMB;
    int ni  = in_sizes[1] / EMB;
    int N   = nu + ni;
    int nnz = in_sizes[2];
    int M   = N + 1;

    // workspace carve-out (256B aligned)
    char*  w   = (char*)d_ws;
    size_t off = 0;
    auto alloc = [&](size_t bytes) -> void* {
        void* p = w + off;
        off = (off + bytes + 255) & ~(size_t)255;
        return p;
    };
    float* embA    = (float*)alloc((size_t)N * EMB * sizeof(float));
    float* embB    = (float*)alloc((size_t)N * EMB * sizeof(float));
    int2*  edges   = (int2*) alloc((size_t)nnz * sizeof(int2));
    int*   cnt     = (int*)  alloc((size_t)M * sizeof(int));
    int*   row_ptr = (int*)  alloc((size_t)M * sizeof(int));
    int*   cursor  = (int*)  alloc((size_t)N * sizeof(int));
    int*   bsum    = (int*)  alloc(1024 * sizeof(int));
    float* acc     = (float*)d_out;   // accumulator lives in the output buffer

    hipMemsetAsync(cnt, 0, (size_t)M * sizeof(int), stream);

    hist_kernel<<<(nnz + 255) / 256, 256, 0, stream>>>(rows, cnt, nnz);

    int nb = (M + 2047) / 2048;
    scan1<<<nb, 256, 0, stream>>>(cnt, bsum, M);
    scan2<<<1,  256, 0, stream>>>(bsum, nb);
    scan3<<<nb, 256, 0, stream>>>(cnt, bsum, row_ptr, cursor, M);

    scatter_kernel<<<(nnz + 255) / 256, 256, 0, stream>>>(rows, cols, vals, cursor, edges, nnz);

    int lgrid = (N + 3) / 4;   // 4 waves (rows) per 256-thread block
    layer_kernel<0><<<lgrid, 256, 0, stream>>>(row_ptr, edges, nullptr, ue, ie, embA, acc, N, nu);
    layer_kernel<1><<<lgrid, 256, 0, stream>>>(row_ptr, edges, embA, ue, ie, embB, acc, N, nu);
    layer_kernel<2><<<lgrid, 256, 0, stream>>>(row_ptr, edges, embB, ue, ie, nullptr, acc, N, nu);
}